// Round 8
// baseline (746.930 us; speedup 1.0000x reference)
//
#include <hip/hip_runtime.h>
#include <stdint.h>

#define BB   2
#define SS   2048
#define DD   1024
#define NH   16
#define RK   204
#define RKP  256
#define HDIM 64
#define BH   (BB*NH)

typedef __attribute__((ext_vector_type(8))) short short8;
typedef __attribute__((ext_vector_type(4))) float f32x4;
typedef unsigned short u16;
typedef unsigned int   u32;

#define LOG2E  1.4426950408889634f

static __device__ __forceinline__ u32 cvtpk(float lo, float hi) {
    u32 r; asm("v_cvt_pk_bf16_f32 %0, %1, %2" : "=v"(r) : "v"(lo), "v"(hi)); return r;
}
static __device__ __forceinline__ u16 f2bf(float f) { return (u16)cvtpk(f, f); }
static __device__ __forceinline__ u32 pack2(float lo, float hi) { return cvtpk(lo, hi); }
static __device__ __forceinline__ float exp2_hw(float x) {
    float r; asm("v_exp_f32 %0, %1" : "=v"(r) : "v"(x)); return r;
}

// ---------------- combined conversion kernel (one launch) ----------------
struct C8 { const float* s[8]; u16* d[8]; };

__global__ void cvt_all_k(C8 c) {
    int y = blockIdx.y;
    int i = blockIdx.x * blockDim.x + threadIdx.x;
    if (y < 4) {
        if (i < RK*DD/4) {
            float4 f = ((const float4*)c.s[y])[i];
            ((uint2*)c.d[y])[i] = make_uint2(pack2(f.x, f.y), pack2(f.z, f.w));
        }
    } else {
        if (i < DD*RKP) {
            int row = i >> 8, col = i & (RKP - 1);
            c.d[y][i] = (col < RK) ? f2bf(c.s[y][row * RK + col]) : (u16)0;
        }
    }
}

// ---------------- z-batched NT GEMM, BK=128 ----------------
struct B3 {
    const void *A0, *A1, *A2;
    const u16  *B0, *B1, *B2;
    const float *bb0, *bb1, *bb2;
    void *C0, *C1, *C2;
};

#define LDW 136   // 128 + 8 u16 pad

template<int A_F32, int OUT_F32, int HAS_BIAS, int VT_LAST, int QSC>
__global__ __launch_bounds__(256)
void gemm_nt_k(B3 g, int lda, int ldb, int nrowsB, int ldc, int K)
{
    const int z = blockIdx.z;
    const void* Ap  = (z==0)?g.A0:(z==1)?g.A1:g.A2;
    const u16*  Bp  = (z==0)?g.B0:(z==1)?g.B1:g.B2;
    const float* bias = (z==0)?g.bb0:(z==1)?g.bb1:g.bb2;
    void* Cp = (z==0)?g.C0:(z==1)?g.C1:g.C2;

    __shared__ __align__(16) u16 As[64*LDW];
    __shared__ __align__(16) u16 Bs[64*LDW];
    const int row0 = blockIdx.x * 64;
    const int col0 = blockIdx.y * 64;
    const int t = threadIdx.x;
    const int w = t >> 6, lane = t & 63, quad = lane >> 4, l16 = lane & 15;
    const int r = t >> 2, seg = t & 3;

    f32x4 acc0 = 0.f, acc1 = 0.f, acc2 = 0.f, acc3 = 0.f;

    for (int k0 = 0; k0 < K; k0 += 128) {
        __syncthreads();
        if (A_F32) {
            const float* ga = (const float*)Ap + (size_t)(row0 + r) * lda + k0 + seg*32;
            float4 f0 = ((const float4*)ga)[0];
            float4 f1 = ((const float4*)ga)[1];
            float4 f2 = ((const float4*)ga)[2];
            float4 f3 = ((const float4*)ga)[3];
            float4 f4 = ((const float4*)ga)[4];
            float4 f5 = ((const float4*)ga)[5];
            float4 f6 = ((const float4*)ga)[6];
            float4 f7 = ((const float4*)ga)[7];
            uint4 s0 = { pack2(f0.x,f0.y), pack2(f0.z,f0.w), pack2(f1.x,f1.y), pack2(f1.z,f1.w) };
            uint4 s1 = { pack2(f2.x,f2.y), pack2(f2.z,f2.w), pack2(f3.x,f3.y), pack2(f3.z,f3.w) };
            uint4 s2 = { pack2(f4.x,f4.y), pack2(f4.z,f4.w), pack2(f5.x,f5.y), pack2(f5.z,f5.w) };
            uint4 s3 = { pack2(f6.x,f6.y), pack2(f6.z,f6.w), pack2(f7.x,f7.y), pack2(f7.z,f7.w) };
            *(uint4*)(As + r*LDW + seg*32)      = s0;
            *(uint4*)(As + r*LDW + seg*32 + 8)  = s1;
            *(uint4*)(As + r*LDW + seg*32 + 16) = s2;
            *(uint4*)(As + r*LDW + seg*32 + 24) = s3;
        } else {
            const u16* ga = (const u16*)Ap + (size_t)(row0 + r) * lda + k0 + seg*32;
            *(uint4*)(As + r*LDW + seg*32)      = ((const uint4*)ga)[0];
            *(uint4*)(As + r*LDW + seg*32 + 8)  = ((const uint4*)ga)[1];
            *(uint4*)(As + r*LDW + seg*32 + 16) = ((const uint4*)ga)[2];
            *(uint4*)(As + r*LDW + seg*32 + 24) = ((const uint4*)ga)[3];
        }
        {
            uint4 b0 = {0,0,0,0}, b1 = {0,0,0,0}, b2 = {0,0,0,0}, b3 = {0,0,0,0};
            if (col0 + r < nrowsB) {
                const u16* gb = Bp + (size_t)(col0 + r) * ldb + k0 + seg*32;
                b0 = ((const uint4*)gb)[0];
                b1 = ((const uint4*)gb)[1];
                b2 = ((const uint4*)gb)[2];
                b3 = ((const uint4*)gb)[3];
            }
            *(uint4*)(Bs + r*LDW + seg*32)      = b0;
            *(uint4*)(Bs + r*LDW + seg*32 + 8)  = b1;
            *(uint4*)(Bs + r*LDW + seg*32 + 16) = b2;
            *(uint4*)(Bs + r*LDW + seg*32 + 24) = b3;
        }
        __syncthreads();
        #pragma unroll
        for (int c = 0; c < 4; ++c) {
            short8 a = *(const short8*)(As + (w*16 + l16)*LDW + c*32 + quad*8);
            short8 b0v = *(const short8*)(Bs + (0*16 + l16)*LDW + c*32 + quad*8);
            acc0 = __builtin_amdgcn_mfma_f32_16x16x32_bf16(a, b0v, acc0, 0, 0, 0);
            short8 b1v = *(const short8*)(Bs + (1*16 + l16)*LDW + c*32 + quad*8);
            acc1 = __builtin_amdgcn_mfma_f32_16x16x32_bf16(a, b1v, acc1, 0, 0, 0);
            short8 b2v = *(const short8*)(Bs + (2*16 + l16)*LDW + c*32 + quad*8);
            acc2 = __builtin_amdgcn_mfma_f32_16x16x32_bf16(a, b2v, acc2, 0, 0, 0);
            short8 b3v = *(const short8*)(Bs + (3*16 + l16)*LDW + c*32 + quad*8);
            acc3 = __builtin_amdgcn_mfma_f32_16x16x32_bf16(a, b3v, acc3, 0, 0, 0);
        }
    }

    if (VT_LAST && z == 2) {
        __syncthreads();
        #pragma unroll
        for (int f = 0; f < 4; ++f) {
            f32x4 a = (f==0) ? acc0 : (f==1) ? acc1 : (f==2) ? acc2 : acc3;
            int col = f*16 + l16;
            float bv = HAS_BIAS ? bias[col0 + col] : 0.f;
            #pragma unroll
            for (int rg = 0; rg < 4; ++rg) {
                int rowl = w*16 + quad*4 + rg;
                As[col*72 + rowl] = f2bf(a[rg] + bv);
            }
        }
        __syncthreads();
        const int b_ = row0 >> 11;
        const int s0 = row0 & (SS - 1);
        const int h  = col0 >> 6;
        u16* dst = (u16*)Cp + ((size_t)((b_*NH + h)*HDIM + r))*SS + s0 + seg*16;
        ((uint4*)dst)[0] = *(const uint4*)(As + r*72 + seg*16);
        ((uint4*)dst)[1] = *(const uint4*)(As + r*72 + seg*16 + 8);
        return;
    }

    const float osc = (QSC && z == 0) ? 0.125f : 1.f;
    #pragma unroll
    for (int f = 0; f < 4; ++f) {
        f32x4 a = (f==0) ? acc0 : (f==1) ? acc1 : (f==2) ? acc2 : acc3;
        int col = col0 + f*16 + l16;
        float bv = HAS_BIAS ? bias[col] : 0.f;
        #pragma unroll
        for (int rg = 0; rg < 4; ++rg) {
            int rowg = row0 + w*16 + quad*4 + rg;
            float val = (a[rg] + bv) * osc;
            if (col >= nrowsB) val = 0.f;
            if (OUT_F32) ((float*)Cp)[(size_t)rowg*ldc + col] = val;
            else         ((u16*)Cp)[(size_t)rowg*ldc + col]  = f2bf(val);
        }
    }
}

// ---------------- fused attention, QBLK=128, 8 waves, SWAPPED QK^T ----------------
// sa_f[rg] = S[k = kbase + f*16 + quad*4 + rg][q = qbase + w*16 + l16]
#define QKTS_8(BUF,sa0,sa1,sa2,sa3) do { \
    short8 b0 = *(const short8*)(BUF + (0*16 + l16)*72 + quad*8); \
    sa0 = __builtin_amdgcn_mfma_f32_16x16x32_bf16(b0, q0, sa0, 0,0,0); \
    short8 b0b = *(const short8*)(BUF + (0*16 + l16)*72 + 32 + quad*8); \
    sa0 = __builtin_amdgcn_mfma_f32_16x16x32_bf16(b0b, q1, sa0, 0,0,0); \
    short8 b1 = *(const short8*)(BUF + (1*16 + l16)*72 + quad*8); \
    sa1 = __builtin_amdgcn_mfma_f32_16x16x32_bf16(b1, q0, sa1, 0,0,0); \
    short8 b1b = *(const short8*)(BUF + (1*16 + l16)*72 + 32 + quad*8); \
    sa1 = __builtin_amdgcn_mfma_f32_16x16x32_bf16(b1b, q1, sa1, 0,0,0); \
    short8 b2 = *(const short8*)(BUF + (2*16 + l16)*72 + quad*8); \
    sa2 = __builtin_amdgcn_mfma_f32_16x16x32_bf16(b2, q0, sa2, 0,0,0); \
    short8 b2b = *(const short8*)(BUF + (2*16 + l16)*72 + 32 + quad*8); \
    sa2 = __builtin_amdgcn_mfma_f32_16x16x32_bf16(b2b, q1, sa2, 0,0,0); \
    short8 b3 = *(const short8*)(BUF + (3*16 + l16)*72 + quad*8); \
    sa3 = __builtin_amdgcn_mfma_f32_16x16x32_bf16(b3, q0, sa3, 0,0,0); \
    short8 b3b = *(const short8*)(BUF + (3*16 + l16)*72 + 32 + quad*8); \
    sa3 = __builtin_amdgcn_mfma_f32_16x16x32_bf16(b3b, q1, sa3, 0,0,0); \
} while (0)

__global__ __launch_bounds__(512)
void attn_k(const u16* __restrict__ qh, const u16* __restrict__ kh,
            const u16* __restrict__ vT,
            float* __restrict__ attn_out, u16* __restrict__ Ob)
{
    __shared__ __align__(16) u16 Ks[64*72];
    __shared__ __align__(16) u16 Vs[64*72];
    __shared__ __align__(16) u16 Ps[128*72];
    const int blk = blockIdx.x;          // bh*16 + i
    const int i_ = blk & 15, bh = blk >> 4;
    const int b_ = bh >> 4, h = bh & (NH - 1);
    const int qbase = i_ * 128;
    const int qtTop = 2*i_ + 1;          // last k-tile index (odd)
    const int t = threadIdx.x, w = t >> 6, lane = t & 63, quad = lane >> 4, l16 = lane & 15;
    const int rs = t >> 3, seg8 = t & 7;
    const int r2 = t >> 2, seg = t & 3;

    // q is pre-scaled by 1/8 at the projection epilogue (exact power-of-2)
    const u16* qrow = qh + (size_t)(b_*SS + qbase + w*16 + l16)*DD + h*HDIM;
    short8 q0 = *(const short8*)(qrow + quad*8);
    short8 q1 = *(const short8*)(qrow + 32 + quad*8);

    const u16* kstage = kh + (size_t)(b_*SS + rs)*DD + h*HDIM + seg8*8;
    const u16* vstage = vT + ((size_t)(bh*HDIM + rs))*SS + seg8*8;
    const int qg = qbase + w*16 + l16;        // this lane's q-row (swapped layout)

    // ---------------- phase 1: per-lane sum l over this lane's k-subset ----------------
    float l1 = 0.f;

    for (int kt0 = 0; kt0 <= qtTop; kt0 += 2) {
        __syncthreads();
        {
            const u16* krow = kstage + (size_t)kt0*64*DD;
            *(uint4*)(Ks + rs*72 + seg8*8) = *(const uint4*)krow;
            *(uint4*)(Vs + rs*72 + seg8*8) = *(const uint4*)(krow + (size_t)64*DD);
        }
        __syncthreads();
        #pragma unroll
        for (int half = 0; half < 2; ++half) {
            const u16* BUF = half ? Vs : Ks;
            int kt = kt0 + half;
            f32x4 sa0 = 0.f, sa1 = 0.f, sa2 = 0.f, sa3 = 0.f;
            QKTS_8(BUF, sa0, sa1, sa2, sa3);
            if (kt < 2*i_) {
                #pragma unroll
                for (int f = 0; f < 4; ++f) {
                    f32x4 sv = (f==0)?sa0:(f==1)?sa1:(f==2)?sa2:sa3;
                    l1 += (exp2_hw(sv[0]*LOG2E) + exp2_hw(sv[1]*LOG2E))
                        + (exp2_hw(sv[2]*LOG2E) + exp2_hw(sv[3]*LOG2E));
                }
            } else {
                int kb = kt*64 + quad*4;
                #pragma unroll
                for (int f = 0; f < 4; ++f) {
                    f32x4 sv = (f==0)?sa0:(f==1)?sa1:(f==2)?sa2:sa3;
                    int key = kb + f*16;
                    float e0 = (key     <= qg) ? exp2_hw(sv[0]*LOG2E) : 0.f;
                    float e1 = (key + 1 <= qg) ? exp2_hw(sv[1]*LOG2E) : 0.f;
                    float e2 = (key + 2 <= qg) ? exp2_hw(sv[2]*LOG2E) : 0.f;
                    float e3 = (key + 3 <= qg) ? exp2_hw(sv[3]*LOG2E) : 0.f;
                    l1 += (e0+e1) + (e2+e3);
                }
            }
        }
    }

    // 4-quad merge (quads share a q-row); fold 1/l into exponent
    l1 += __shfl_xor(l1, 16);
    l1 += __shfl_xor(l1, 32);
    const float lg2rl = -__log2f(l1);

    // ---------------- phase 2: P write (dwordx4) + O = P*V ----------------
    f32x4 oa0 = 0.f, oa1 = 0.f, oa2 = 0.f, oa3 = 0.f;
    float* attn_base = attn_out + (size_t)bh * SS * SS;
    float* pr = attn_base + (size_t)qg*SS + quad*4;   // lane's row, its 4-col segment
    u16* psw = Ps + (w*16 + l16)*72 + quad*4;         // lane's Ps row segment (8B aligned)

    for (int kt = 0; kt <= qtTop; ++kt) {
        __syncthreads();
        {
            const u16* krow = kstage + (size_t)kt*64*DD;
            *(uint4*)(Ks + rs*72 + seg8*8) = *(const uint4*)krow;
            const u16* vrow = vstage + kt*64;
            *(uint4*)(Vs + rs*72 + seg8*8) = *(const uint4*)vrow;
        }
        __syncthreads();

        f32x4 sa0 = 0.f, sa1 = 0.f, sa2 = 0.f, sa3 = 0.f;
        QKTS_8(Ks, sa0, sa1, sa2, sa3);

        if (kt < 2*i_) {
            #pragma unroll
            for (int f = 0; f < 4; ++f) {
                f32x4 sv = (f==0)?sa0:(f==1)?sa1:(f==2)?sa2:sa3;
                f32x4 pv;
                pv[0] = exp2_hw(__builtin_fmaf(sv[0], LOG2E, lg2rl));
                pv[1] = exp2_hw(__builtin_fmaf(sv[1], LOG2E, lg2rl));
                pv[2] = exp2_hw(__builtin_fmaf(sv[2], LOG2E, lg2rl));
                pv[3] = exp2_hw(__builtin_fmaf(sv[3], LOG2E, lg2rl));
                *(f32x4*)(pr + f*16) = pv;
                uint2 pk = make_uint2(cvtpk(pv[0], pv[1]), cvtpk(pv[2], pv[3]));
                *(uint2*)(psw + f*16) = pk;
            }
        } else {
            int kb = kt*64 + quad*4;
            #pragma unroll
            for (int f = 0; f < 4; ++f) {
                f32x4 sv = (f==0)?sa0:(f==1)?sa1:(f==2)?sa2:sa3;
                int key = kb + f*16;
                f32x4 pv;
                pv[0] = (key     <= qg) ? exp2_hw(__builtin_fmaf(sv[0], LOG2E, lg2rl)) : 0.f;
                pv[1] = (key + 1 <= qg) ? exp2_hw(__builtin_fmaf(sv[1], LOG2E, lg2rl)) : 0.f;
                pv[2] = (key + 2 <= qg) ? exp2_hw(__builtin_fmaf(sv[2], LOG2E, lg2rl)) : 0.f;
                pv[3] = (key + 3 <= qg) ? exp2_hw(__builtin_fmaf(sv[3], LOG2E, lg2rl)) : 0.f;
                *(f32x4*)(pr + f*16) = pv;
                uint2 pk = make_uint2(cvtpk(pv[0], pv[1]), cvtpk(pv[2], pv[3]));
                *(uint2*)(psw + f*16) = pk;
            }
        }
        pr += 64;

        // Ps rows are wave-private (wave w writes and reads rows w*16..w*16+15);
        // per-wave LDS pipe is in-order — compiler-level fence only, no barrier.
        asm volatile("" ::: "memory");

        // O += P * V
        #pragma unroll
        for (int c = 0; c < 2; ++c) {
            short8 pa = *(const short8*)(Ps + (w*16 + l16)*72 + c*32 + quad*8);
            short8 v0 = *(const short8*)(Vs + (0*16 + l16)*72 + c*32 + quad*8);
            oa0 = __builtin_amdgcn_mfma_f32_16x16x32_bf16(pa, v0, oa0, 0,0,0);
            short8 v1 = *(const short8*)(Vs + (1*16 + l16)*72 + c*32 + quad*8);
            oa1 = __builtin_amdgcn_mfma_f32_16x16x32_bf16(pa, v1, oa1, 0,0,0);
            short8 v2 = *(const short8*)(Vs + (2*16 + l16)*72 + c*32 + quad*8);
            oa2 = __builtin_amdgcn_mfma_f32_16x16x32_bf16(pa, v2, oa2, 0,0,0);
            short8 v3 = *(const short8*)(Vs + (3*16 + l16)*72 + c*32 + quad*8);
            oa3 = __builtin_amdgcn_mfma_f32_16x16x32_bf16(pa, v3, oa3, 0,0,0);
        }
    }

    // fully-masked upper tiles: explicit zeros (d_out is poisoned)
    for (int kt = qtTop + 1; kt < 32; ++kt) {
        int kbase = kt * 64;
        f32x4 z = 0.f;
        f32x4* p = (f32x4*)(attn_base + (size_t)(qbase + r2)*SS + kbase + seg*16);
        p[0] = z; p[1] = z; p[2] = z; p[3] = z;
    }

    #pragma unroll
    for (int f = 0; f < 4; ++f) {
        f32x4 ov = (f==0) ? oa0 : (f==1) ? oa1 : (f==2) ? oa2 : oa3;
        #pragma unroll
        for (int rg = 0; rg < 4; ++rg) {
            int qgo = qbase + w*16 + quad*4 + rg;
            Ob[(size_t)(b_*SS + qgo)*DD + h*HDIM + f*16 + l16] = f2bf(ov[rg]);
        }
    }
}

// ---------------- launch ----------------
extern "C" void kernel_launch(void* const* d_in, const int* in_sizes, int n_in,
                              void* d_out, int out_size, void* d_ws, size_t ws_size,
                              hipStream_t stream)
{
    const float* xs[3] = { (const float*)d_in[0], (const float*)d_in[1], (const float*)d_in[2] };
    const float* Vw[4] = { (const float*)d_in[3], (const float*)d_in[6], (const float*)d_in[9],  (const float*)d_in[12] };
    const float* Uw[4] = { (const float*)d_in[4], (const float*)d_in[7], (const float*)d_in[10], (const float*)d_in[13] };
    const float* bw[4] = { (const float*)d_in[5], (const float*)d_in[8], (const float*)d_in[11], (const float*)d_in[14] };

    char* ws = (char*)d_ws;
    size_t off = 0;
    auto alloc = [&](size_t bytes) -> char* {
        char* p = ws + off;
        off += (bytes + 255) & ~(size_t)255;
        return p;
    };
    u16* wV[4]; for (int i = 0; i < 4; ++i) wV[i] = (u16*)alloc((size_t)RK*DD*2);
    u16* wU[4]; for (int i = 0; i < 4; ++i) wU[i] = (u16*)alloc((size_t)DD*RKP*2);
    u16* Tb[3]; for (int i = 0; i < 3; ++i) Tb[i] = (u16*)alloc((size_t)BB*SS*RKP*2);
    u16* hb[2]; for (int i = 0; i < 2; ++i) hb[i] = (u16*)alloc((size_t)BB*SS*DD*2);
    u16* vTb = (u16*)alloc((size_t)BB*SS*DD*2);
    u16* Ob  = (u16*)alloc((size_t)BB*SS*DD*2);
    (void)ws_size; (void)in_sizes; (void)n_in; (void)out_size;

    // weight conversions: single launch, y 0..3 = V bf16, y 4..7 = U pad
    {
        C8 c = { { Vw[0], Vw[1], Vw[2], Vw[3], Uw[0], Uw[1], Uw[2], Uw[3] },
                 { wV[0], wV[1], wV[2], wV[3], wU[0], wU[1], wU[2], wU[3] } };
        cvt_all_k<<<dim3((DD*RKP + 255)/256, 8), 256, 0, stream>>>(c);
    }

    const int MROWS = BB*SS;           // 4096
    // stage 1 (q,k,v batched over z): X @ V^T -> T[4096x256 padded]
    {
        B3 g = { xs[0], xs[1], xs[2], wV[0], wV[1], wV[2],
                 nullptr, nullptr, nullptr, Tb[0], Tb[1], Tb[2] };
        gemm_nt_k<1,0,0,0,0><<<dim3(MROWS/64, RKP/64, 3), 256, 0, stream>>>(
            g, DD, DD, RK, RKP, DD);
    }
    // stage 2 (batched): T @ U^T + b -> qh (scaled 1/8), kh, vT (transposed epilogue)
    {
        B3 g = { Tb[0], Tb[1], Tb[2], wU[0], wU[1], wU[2],
                 bw[0], bw[1], bw[2], hb[0], hb[1], vTb };
        gemm_nt_k<0,0,1,1,1><<<dim3(MROWS/64, DD/64, 3), 256, 0, stream>>>(
            g, RKP, RKP, DD, DD, RKP);
    }

    float* attn_out = (float*)d_out + (size_t)BB*SS*DD;
    attn_k<<<BH*16, 512, 0, stream>>>(hb[0], hb[1], vTb, attn_out, Ob);

    // output projection: O @ Vo^T -> T; T @ Uo^T + bo -> d_out (fp32)
    {
        B3 g = { Ob, Ob, Ob, wV[3], wV[3], wV[3],
                 nullptr, nullptr, nullptr, Tb[0], Tb[0], Tb[0] };
        gemm_nt_k<0,0,0,0,0><<<dim3(MROWS/64, RKP/64, 1), 256, 0, stream>>>(
            g, DD, DD, RK, RKP, DD);
    }
    {
        B3 g = { Tb[0], Tb[0], Tb[0], wU[3], wU[3], wU[3],
                 bw[3], bw[3], bw[3], d_out, d_out, d_out };
        gemm_nt_k<0,1,1,0,0><<<dim3(MROWS/64, DD/64, 1), 256, 0, stream>>>(
            g, RKP, RKP, DD, DD, RKP);
    }
}

// Round 9
// 725.818 us; speedup vs baseline: 1.0291x; 1.0291x over previous
//
#include <hip/hip_runtime.h>
#include <stdint.h>

#define BB   2
#define SS   2048
#define DD   1024
#define NH   16
#define RK   204
#define RKP  256
#define HDIM 64
#define BH   (BB*NH)

typedef __attribute__((ext_vector_type(8))) short short8;
typedef __attribute__((ext_vector_type(4))) float f32x4;
typedef unsigned short u16;
typedef unsigned int   u32;

#define LOG2E  1.4426950408889634f

static __device__ __forceinline__ u32 cvtpk(float lo, float hi) {
    u32 r; asm("v_cvt_pk_bf16_f32 %0, %1, %2" : "=v"(r) : "v"(lo), "v"(hi)); return r;
}
static __device__ __forceinline__ u16 f2bf(float f) { return (u16)cvtpk(f, f); }
static __device__ __forceinline__ u32 pack2(float lo, float hi) { return cvtpk(lo, hi); }
static __device__ __forceinline__ float exp2_hw(float x) {
    float r; asm("v_exp_f32 %0, %1" : "=v"(r) : "v"(x)); return r;
}

// ---------------- combined conversion kernel (one launch) ----------------
struct C8 { const float* s[8]; u16* d[8]; };

__global__ void cvt_all_k(C8 c) {
    int y = blockIdx.y;
    int i = blockIdx.x * blockDim.x + threadIdx.x;
    if (y < 4) {
        if (i < RK*DD/4) {
            float4 f = ((const float4*)c.s[y])[i];
            ((uint2*)c.d[y])[i] = make_uint2(pack2(f.x, f.y), pack2(f.z, f.w));
        }
    } else {
        if (i < DD*RKP) {
            int row = i >> 8, col = i & (RKP - 1);
            c.d[y][i] = (col < RK) ? f2bf(c.s[y][row * RK + col]) : (u16)0;
        }
    }
}

// ---------------- z-batched NT GEMM, BK=128 ----------------
struct B3 {
    const void *A0, *A1, *A2;
    const u16  *B0, *B1, *B2;
    const float *bb0, *bb1, *bb2;
    void *C0, *C1, *C2;
};

#define LDW 136   // 128 + 8 u16 pad

template<int A_F32, int OUT_F32, int HAS_BIAS, int VT_LAST, int QSC>
__global__ __launch_bounds__(256)
void gemm_nt_k(B3 g, int lda, int ldb, int nrowsB, int ldc, int K)
{
    const int z = blockIdx.z;
    const void* Ap  = (z==0)?g.A0:(z==1)?g.A1:g.A2;
    const u16*  Bp  = (z==0)?g.B0:(z==1)?g.B1:g.B2;
    const float* bias = (z==0)?g.bb0:(z==1)?g.bb1:g.bb2;
    void* Cp = (z==0)?g.C0:(z==1)?g.C1:g.C2;

    __shared__ __align__(16) u16 As[64*LDW];
    __shared__ __align__(16) u16 Bs[64*LDW];
    const int row0 = blockIdx.x * 64;
    const int col0 = blockIdx.y * 64;
    const int t = threadIdx.x;
    const int w = t >> 6, lane = t & 63, quad = lane >> 4, l16 = lane & 15;
    const int r = t >> 2, seg = t & 3;

    f32x4 acc0 = 0.f, acc1 = 0.f, acc2 = 0.f, acc3 = 0.f;

    for (int k0 = 0; k0 < K; k0 += 128) {
        __syncthreads();
        if (A_F32) {
            const float* ga = (const float*)Ap + (size_t)(row0 + r) * lda + k0 + seg*32;
            float4 f0 = ((const float4*)ga)[0];
            float4 f1 = ((const float4*)ga)[1];
            float4 f2 = ((const float4*)ga)[2];
            float4 f3 = ((const float4*)ga)[3];
            float4 f4 = ((const float4*)ga)[4];
            float4 f5 = ((const float4*)ga)[5];
            float4 f6 = ((const float4*)ga)[6];
            float4 f7 = ((const float4*)ga)[7];
            uint4 s0 = { pack2(f0.x,f0.y), pack2(f0.z,f0.w), pack2(f1.x,f1.y), pack2(f1.z,f1.w) };
            uint4 s1 = { pack2(f2.x,f2.y), pack2(f2.z,f2.w), pack2(f3.x,f3.y), pack2(f3.z,f3.w) };
            uint4 s2 = { pack2(f4.x,f4.y), pack2(f4.z,f4.w), pack2(f5.x,f5.y), pack2(f5.z,f5.w) };
            uint4 s3 = { pack2(f6.x,f6.y), pack2(f6.z,f6.w), pack2(f7.x,f7.y), pack2(f7.z,f7.w) };
            *(uint4*)(As + r*LDW + seg*32)      = s0;
            *(uint4*)(As + r*LDW + seg*32 + 8)  = s1;
            *(uint4*)(As + r*LDW + seg*32 + 16) = s2;
            *(uint4*)(As + r*LDW + seg*32 + 24) = s3;
        } else {
            const u16* ga = (const u16*)Ap + (size_t)(row0 + r) * lda + k0 + seg*32;
            *(uint4*)(As + r*LDW + seg*32)      = ((const uint4*)ga)[0];
            *(uint4*)(As + r*LDW + seg*32 + 8)  = ((const uint4*)ga)[1];
            *(uint4*)(As + r*LDW + seg*32 + 16) = ((const uint4*)ga)[2];
            *(uint4*)(As + r*LDW + seg*32 + 24) = ((const uint4*)ga)[3];
        }
        {
            uint4 b0 = {0,0,0,0}, b1 = {0,0,0,0}, b2 = {0,0,0,0}, b3 = {0,0,0,0};
            if (col0 + r < nrowsB) {
                const u16* gb = Bp + (size_t)(col0 + r) * ldb + k0 + seg*32;
                b0 = ((const uint4*)gb)[0];
                b1 = ((const uint4*)gb)[1];
                b2 = ((const uint4*)gb)[2];
                b3 = ((const uint4*)gb)[3];
            }
            *(uint4*)(Bs + r*LDW + seg*32)      = b0;
            *(uint4*)(Bs + r*LDW + seg*32 + 8)  = b1;
            *(uint4*)(Bs + r*LDW + seg*32 + 16) = b2;
            *(uint4*)(Bs + r*LDW + seg*32 + 24) = b3;
        }
        __syncthreads();
        #pragma unroll
        for (int c = 0; c < 4; ++c) {
            short8 a = *(const short8*)(As + (w*16 + l16)*LDW + c*32 + quad*8);
            short8 b0v = *(const short8*)(Bs + (0*16 + l16)*LDW + c*32 + quad*8);
            acc0 = __builtin_amdgcn_mfma_f32_16x16x32_bf16(a, b0v, acc0, 0, 0, 0);
            short8 b1v = *(const short8*)(Bs + (1*16 + l16)*LDW + c*32 + quad*8);
            acc1 = __builtin_amdgcn_mfma_f32_16x16x32_bf16(a, b1v, acc1, 0, 0, 0);
            short8 b2v = *(const short8*)(Bs + (2*16 + l16)*LDW + c*32 + quad*8);
            acc2 = __builtin_amdgcn_mfma_f32_16x16x32_bf16(a, b2v, acc2, 0, 0, 0);
            short8 b3v = *(const short8*)(Bs + (3*16 + l16)*LDW + c*32 + quad*8);
            acc3 = __builtin_amdgcn_mfma_f32_16x16x32_bf16(a, b3v, acc3, 0, 0, 0);
        }
    }

    if (VT_LAST && z == 2) {
        __syncthreads();
        #pragma unroll
        for (int f = 0; f < 4; ++f) {
            f32x4 a = (f==0) ? acc0 : (f==1) ? acc1 : (f==2) ? acc2 : acc3;
            int col = f*16 + l16;
            float bv = HAS_BIAS ? bias[col0 + col] : 0.f;
            #pragma unroll
            for (int rg = 0; rg < 4; ++rg) {
                int rowl = w*16 + quad*4 + rg;
                As[col*72 + rowl] = f2bf(a[rg] + bv);
            }
        }
        __syncthreads();
        const int b_ = row0 >> 11;
        const int s0 = row0 & (SS - 1);
        const int h  = col0 >> 6;
        u16* dst = (u16*)Cp + ((size_t)((b_*NH + h)*HDIM + r))*SS + s0 + seg*16;
        ((uint4*)dst)[0] = *(const uint4*)(As + r*72 + seg*16);
        ((uint4*)dst)[1] = *(const uint4*)(As + r*72 + seg*16 + 8);
        return;
    }

    const float osc = (QSC && z == 0) ? 0.125f : 1.f;
    #pragma unroll
    for (int f = 0; f < 4; ++f) {
        f32x4 a = (f==0) ? acc0 : (f==1) ? acc1 : (f==2) ? acc2 : acc3;
        int col = col0 + f*16 + l16;
        float bv = HAS_BIAS ? bias[col] : 0.f;
        #pragma unroll
        for (int rg = 0; rg < 4; ++rg) {
            int rowg = row0 + w*16 + quad*4 + rg;
            float val = (a[rg] + bv) * osc;
            if (col >= nrowsB) val = 0.f;
            if (OUT_F32) ((float*)Cp)[(size_t)rowg*ldc + col] = val;
            else         ((u16*)Cp)[(size_t)rowg*ldc + col]  = f2bf(val);
        }
    }
}

// ---------------- fused attention, QBLK=128, 8 waves, swapped QK^T, async-prefetch ----
// sa_f[rg] = S[k = kbase + f*16 + quad*4 + rg][q = qbase + w*16 + l16]
#define QKTS_8(BUF,sa0,sa1,sa2,sa3) do { \
    short8 b0 = *(const short8*)(BUF + (0*16 + l16)*72 + quad*8); \
    sa0 = __builtin_amdgcn_mfma_f32_16x16x32_bf16(b0, q0, sa0, 0,0,0); \
    short8 b0b = *(const short8*)(BUF + (0*16 + l16)*72 + 32 + quad*8); \
    sa0 = __builtin_amdgcn_mfma_f32_16x16x32_bf16(b0b, q1, sa0, 0,0,0); \
    short8 b1 = *(const short8*)(BUF + (1*16 + l16)*72 + quad*8); \
    sa1 = __builtin_amdgcn_mfma_f32_16x16x32_bf16(b1, q0, sa1, 0,0,0); \
    short8 b1b = *(const short8*)(BUF + (1*16 + l16)*72 + 32 + quad*8); \
    sa1 = __builtin_amdgcn_mfma_f32_16x16x32_bf16(b1b, q1, sa1, 0,0,0); \
    short8 b2 = *(const short8*)(BUF + (2*16 + l16)*72 + quad*8); \
    sa2 = __builtin_amdgcn_mfma_f32_16x16x32_bf16(b2, q0, sa2, 0,0,0); \
    short8 b2b = *(const short8*)(BUF + (2*16 + l16)*72 + 32 + quad*8); \
    sa2 = __builtin_amdgcn_mfma_f32_16x16x32_bf16(b2b, q1, sa2, 0,0,0); \
    short8 b3 = *(const short8*)(BUF + (3*16 + l16)*72 + quad*8); \
    sa3 = __builtin_amdgcn_mfma_f32_16x16x32_bf16(b3, q0, sa3, 0,0,0); \
    short8 b3b = *(const short8*)(BUF + (3*16 + l16)*72 + 32 + quad*8); \
    sa3 = __builtin_amdgcn_mfma_f32_16x16x32_bf16(b3b, q1, sa3, 0,0,0); \
} while (0)

__global__ __launch_bounds__(512)
void attn_k(const u16* __restrict__ qh, const u16* __restrict__ kh,
            const u16* __restrict__ vT,
            float* __restrict__ attn_out, u16* __restrict__ Ob)
{
    __shared__ __align__(16) u16 Ks[64*72];
    __shared__ __align__(16) u16 Vs[64*72];
    __shared__ __align__(16) u16 Ps[128*72];
    const int blk = blockIdx.x;          // bh*16 + i
    const int i_ = blk & 15, bh = blk >> 4;
    const int b_ = bh >> 4, h = bh & (NH - 1);
    const int qbase = i_ * 128;
    const int qtTop = 2*i_ + 1;          // last k-tile index (odd)
    const int t = threadIdx.x, w = t >> 6, lane = t & 63, quad = lane >> 4, l16 = lane & 15;
    const int rs = t >> 3, seg8 = t & 7;
    const int r2 = t >> 2, seg = t & 3;

    // q is pre-scaled by 1/8 at the projection epilogue (exact power-of-2)
    const u16* qrow = qh + (size_t)(b_*SS + qbase + w*16 + l16)*DD + h*HDIM;
    short8 q0 = *(const short8*)(qrow + quad*8);
    short8 q1 = *(const short8*)(qrow + 32 + quad*8);

    const u16* kstage = kh + (size_t)(b_*SS + rs)*DD + h*HDIM + seg8*8;
    const u16* vstage = vT + ((size_t)(bh*HDIM + rs))*SS + seg8*8;
    const int qg = qbase + w*16 + l16;        // this lane's q-row (swapped layout)

    // ---------------- phase 1: per-lane sum l; prefetch next pair under compute ----------
    float l1 = 0.f;
    uint4 kreg = *(const uint4*)kstage;                      // tile 0
    uint4 vreg = *(const uint4*)(kstage + (size_t)64*DD);    // tile 1 (qtTop>=1 always)

    for (int kt0 = 0; kt0 <= qtTop; kt0 += 2) {
        __syncthreads();
        *(uint4*)(Ks + rs*72 + seg8*8) = kreg;
        *(uint4*)(Vs + rs*72 + seg8*8) = vreg;
        if (kt0 + 2 <= qtTop) {                              // issue next pair early
            const u16* krow = kstage + (size_t)(kt0+2)*64*DD;
            kreg = *(const uint4*)krow;
            vreg = *(const uint4*)(krow + (size_t)64*DD);
        }
        __syncthreads();
        #pragma unroll
        for (int half = 0; half < 2; ++half) {
            const u16* BUF = half ? Vs : Ks;
            int kt = kt0 + half;
            f32x4 sa0 = 0.f, sa1 = 0.f, sa2 = 0.f, sa3 = 0.f;
            QKTS_8(BUF, sa0, sa1, sa2, sa3);
            if (kt < 2*i_) {
                #pragma unroll
                for (int f = 0; f < 4; ++f) {
                    f32x4 sv = (f==0)?sa0:(f==1)?sa1:(f==2)?sa2:sa3;
                    l1 += (exp2_hw(sv[0]*LOG2E) + exp2_hw(sv[1]*LOG2E))
                        + (exp2_hw(sv[2]*LOG2E) + exp2_hw(sv[3]*LOG2E));
                }
            } else {
                int kb = kt*64 + quad*4;
                #pragma unroll
                for (int f = 0; f < 4; ++f) {
                    f32x4 sv = (f==0)?sa0:(f==1)?sa1:(f==2)?sa2:sa3;
                    int key = kb + f*16;
                    float e0 = (key     <= qg) ? exp2_hw(sv[0]*LOG2E) : 0.f;
                    float e1 = (key + 1 <= qg) ? exp2_hw(sv[1]*LOG2E) : 0.f;
                    float e2 = (key + 2 <= qg) ? exp2_hw(sv[2]*LOG2E) : 0.f;
                    float e3 = (key + 3 <= qg) ? exp2_hw(sv[3]*LOG2E) : 0.f;
                    l1 += (e0+e1) + (e2+e3);
                }
            }
        }
    }

    // 4-quad merge (quads share a q-row); fold 1/l into exponent
    l1 += __shfl_xor(l1, 16);
    l1 += __shfl_xor(l1, 32);
    const float lg2rl = -__log2f(l1);

    // ---------------- phase 2: P write (dwordx4) + O = P*V; prefetch next tile ----------
    f32x4 oa0 = 0.f, oa1 = 0.f, oa2 = 0.f, oa3 = 0.f;
    float* attn_base = attn_out + (size_t)bh * SS * SS;
    float* pr = attn_base + (size_t)qg*SS + quad*4;   // lane's row, its 4-col segment
    u16* psw = Ps + (w*16 + l16)*72 + quad*4;         // lane's Ps row segment (8B aligned)

    kreg = *(const uint4*)kstage;
    vreg = *(const uint4*)vstage;

    for (int kt = 0; kt <= qtTop; ++kt) {
        __syncthreads();
        *(uint4*)(Ks + rs*72 + seg8*8) = kreg;
        *(uint4*)(Vs + rs*72 + seg8*8) = vreg;
        if (kt + 1 <= qtTop) {                               // issue next tile early
            kreg = *(const uint4*)(kstage + (size_t)(kt+1)*64*DD);
            vreg = *(const uint4*)(vstage + (kt+1)*64);
        }
        __syncthreads();

        f32x4 sa0 = 0.f, sa1 = 0.f, sa2 = 0.f, sa3 = 0.f;
        QKTS_8(Ks, sa0, sa1, sa2, sa3);

        if (kt < 2*i_) {
            #pragma unroll
            for (int f = 0; f < 4; ++f) {
                f32x4 sv = (f==0)?sa0:(f==1)?sa1:(f==2)?sa2:sa3;
                f32x4 pv;
                pv[0] = exp2_hw(__builtin_fmaf(sv[0], LOG2E, lg2rl));
                pv[1] = exp2_hw(__builtin_fmaf(sv[1], LOG2E, lg2rl));
                pv[2] = exp2_hw(__builtin_fmaf(sv[2], LOG2E, lg2rl));
                pv[3] = exp2_hw(__builtin_fmaf(sv[3], LOG2E, lg2rl));
                *(f32x4*)(pr + f*16) = pv;
                uint2 pk = make_uint2(cvtpk(pv[0], pv[1]), cvtpk(pv[2], pv[3]));
                *(uint2*)(psw + f*16) = pk;
            }
        } else {
            int kb = kt*64 + quad*4;
            #pragma unroll
            for (int f = 0; f < 4; ++f) {
                f32x4 sv = (f==0)?sa0:(f==1)?sa1:(f==2)?sa2:sa3;
                int key = kb + f*16;
                f32x4 pv;
                pv[0] = (key     <= qg) ? exp2_hw(__builtin_fmaf(sv[0], LOG2E, lg2rl)) : 0.f;
                pv[1] = (key + 1 <= qg) ? exp2_hw(__builtin_fmaf(sv[1], LOG2E, lg2rl)) : 0.f;
                pv[2] = (key + 2 <= qg) ? exp2_hw(__builtin_fmaf(sv[2], LOG2E, lg2rl)) : 0.f;
                pv[3] = (key + 3 <= qg) ? exp2_hw(__builtin_fmaf(sv[3], LOG2E, lg2rl)) : 0.f;
                *(f32x4*)(pr + f*16) = pv;
                uint2 pk = make_uint2(cvtpk(pv[0], pv[1]), cvtpk(pv[2], pv[3]));
                *(uint2*)(psw + f*16) = pk;
            }
        }
        pr += 64;

        // Ps rows are wave-private (wave w writes and reads rows w*16..w*16+15);
        // per-wave LDS pipe is in-order — compiler-level fence only, no barrier.
        asm volatile("" ::: "memory");

        // O += P * V
        #pragma unroll
        for (int c = 0; c < 2; ++c) {
            short8 pa = *(const short8*)(Ps + (w*16 + l16)*72 + c*32 + quad*8);
            short8 v0 = *(const short8*)(Vs + (0*16 + l16)*72 + c*32 + quad*8);
            oa0 = __builtin_amdgcn_mfma_f32_16x16x32_bf16(pa, v0, oa0, 0,0,0);
            short8 v1 = *(const short8*)(Vs + (1*16 + l16)*72 + c*32 + quad*8);
            oa1 = __builtin_amdgcn_mfma_f32_16x16x32_bf16(pa, v1, oa1, 0,0,0);
            short8 v2 = *(const short8*)(Vs + (2*16 + l16)*72 + c*32 + quad*8);
            oa2 = __builtin_amdgcn_mfma_f32_16x16x32_bf16(pa, v2, oa2, 0,0,0);
            short8 v3 = *(const short8*)(Vs + (3*16 + l16)*72 + c*32 + quad*8);
            oa3 = __builtin_amdgcn_mfma_f32_16x16x32_bf16(pa, v3, oa3, 0,0,0);
        }
    }

    // fully-masked upper tiles: explicit zeros (d_out is poisoned)
    for (int kt = qtTop + 1; kt < 32; ++kt) {
        int kbase = kt * 64;
        f32x4 z = 0.f;
        f32x4* p = (f32x4*)(attn_base + (size_t)(qbase + r2)*SS + kbase + seg*16);
        p[0] = z; p[1] = z; p[2] = z; p[3] = z;
    }

    #pragma unroll
    for (int f = 0; f < 4; ++f) {
        f32x4 ov = (f==0) ? oa0 : (f==1) ? oa1 : (f==2) ? oa2 : oa3;
        #pragma unroll
        for (int rg = 0; rg < 4; ++rg) {
            int qgo = qbase + w*16 + quad*4 + rg;
            Ob[(size_t)(b_*SS + qgo)*DD + h*HDIM + f*16 + l16] = f2bf(ov[rg]);
        }
    }
}

// ---------------- launch ----------------
extern "C" void kernel_launch(void* const* d_in, const int* in_sizes, int n_in,
                              void* d_out, int out_size, void* d_ws, size_t ws_size,
                              hipStream_t stream)
{
    const float* xs[3] = { (const float*)d_in[0], (const float*)d_in[1], (const float*)d_in[2] };
    const float* Vw[4] = { (const float*)d_in[3], (const float*)d_in[6], (const float*)d_in[9],  (const float*)d_in[12] };
    const float* Uw[4] = { (const float*)d_in[4], (const float*)d_in[7], (const float*)d_in[10], (const float*)d_in[13] };
    const float* bw[4] = { (const float*)d_in[5], (const float*)d_in[8], (const float*)d_in[11], (const float*)d_in[14] };

    char* ws = (char*)d_ws;
    size_t off = 0;
    auto alloc = [&](size_t bytes) -> char* {
        char* p = ws + off;
        off += (bytes + 255) & ~(size_t)255;
        return p;
    };
    u16* wV[4]; for (int i = 0; i < 4; ++i) wV[i] = (u16*)alloc((size_t)RK*DD*2);
    u16* wU[4]; for (int i = 0; i < 4; ++i) wU[i] = (u16*)alloc((size_t)DD*RKP*2);
    u16* Tb[3]; for (int i = 0; i < 3; ++i) Tb[i] = (u16*)alloc((size_t)BB*SS*RKP*2);
    u16* hb[2]; for (int i = 0; i < 2; ++i) hb[i] = (u16*)alloc((size_t)BB*SS*DD*2);
    u16* vTb = (u16*)alloc((size_t)BB*SS*DD*2);
    u16* Ob  = (u16*)alloc((size_t)BB*SS*DD*2);
    (void)ws_size; (void)in_sizes; (void)n_in; (void)out_size;

    // weight conversions: single launch, y 0..3 = V bf16, y 4..7 = U pad
    {
        C8 c = { { Vw[0], Vw[1], Vw[2], Vw[3], Uw[0], Uw[1], Uw[2], Uw[3] },
                 { wV[0], wV[1], wV[2], wV[3], wU[0], wU[1], wU[2], wU[3] } };
        cvt_all_k<<<dim3((DD*RKP + 255)/256, 8), 256, 0, stream>>>(c);
    }

    const int MROWS = BB*SS;           // 4096
    // stage 1 (q,k,v batched over z): X @ V^T -> T[4096x256 padded]
    {
        B3 g = { xs[0], xs[1], xs[2], wV[0], wV[1], wV[2],
                 nullptr, nullptr, nullptr, Tb[0], Tb[1], Tb[2] };
        gemm_nt_k<1,0,0,0,0><<<dim3(MROWS/64, RKP/64, 3), 256, 0, stream>>>(
            g, DD, DD, RK, RKP, DD);
    }
    // stage 2 (batched): T @ U^T + b -> qh (scaled 1/8), kh, vT (transposed epilogue)
    {
        B3 g = { Tb[0], Tb[1], Tb[2], wU[0], wU[1], wU[2],
                 bw[0], bw[1], bw[2], hb[0], hb[1], vTb };
        gemm_nt_k<0,0,1,1,1><<<dim3(MROWS/64, DD/64, 3), 256, 0, stream>>>(
            g, RKP, RKP, DD, DD, RKP);
    }

    float* attn_out = (float*)d_out + (size_t)BB*SS*DD;
    attn_k<<<BH*16, 512, 0, stream>>>(hb[0], hb[1], vTb, attn_out, Ob);

    // output projection: O @ Vo^T -> T; T @ Uo^T + bo -> d_out (fp32)
    {
        B3 g = { Ob, Ob, Ob, wV[3], wV[3], wV[3],
                 nullptr, nullptr, nullptr, Tb[0], Tb[0], Tb[0] };
        gemm_nt_k<0,0,0,0,0><<<dim3(MROWS/64, RKP/64, 1), 256, 0, stream>>>(
            g, DD, DD, RK, RKP, DD);
    }
    {
        B3 g = { Tb[0], Tb[0], Tb[0], wU[3], wU[3], wU[3],
                 bw[3], bw[3], bw[3], d_out, d_out, d_out };
        gemm_nt_k<0,1,1,0,0><<<dim3(MROWS/64, DD/64, 1), 256, 0, stream>>>(
            g, RKP, RKP, DD, DD, RKP);
    }
}